// Round 1
// baseline (709.166 us; speedup 1.0000x reference)
//
#include <hip/hip_runtime.h>
#include <math.h>

// SNN forward: collapse the sequential scan via linearity.
//   u(t)   = x(t) @ W1^T                      (one big GEMM, 16 GFLOP)
//   S(t)   = S(t-1) - S(t-1)*inv1 + u(t)      (filter commutes with matmul)
//   h1     = S + b1 ; v1 = 0.5*v1 + 0.5*h1 ; sp = (v1-1 >= 0); v1 *= (1-sp)
//   s2(t)  = s2 - s2*inv2 + sp
//   v2(T)  = sum_t 0.5^(100-t) * (s2(t)@W2^T + b2)  = z @ W2^T + b2
// with z = sum_t 2^(t-100) * s2(t)  (sum of coeffs = 1-2^-100 == 1.0f)

#define BM 256
#define BK 16
#define NHID 100
#define NSTEPS 100
#define KDIM 784

// ---------------------------------------------------------------------------
// Kernel 1: U = Xflat(102400 x 784) @ W1^T (784 x 100), fp32.
// Block: 256 threads = 4 waves. Wave ng handles output cols [25*ng, 25*ng+25).
// Lane handles rows 4*lane..4*lane+3 of the 256-row tile. TM=4, TN=25:
// per k: 4 ds_read (one b128) + 25 wave-uniform broadcasts -> 100 FMAs.
// ---------------------------------------------------------------------------
__global__ __launch_bounds__(256, 3)
void snn_gemm1(const float* __restrict__ X, const float* __restrict__ W1,
               float* __restrict__ U) {
  __shared__ float Xs[BK][BM + 4];   // +4 pad: keeps 16B alignment, breaks write conflicts
  __shared__ float Ws[4][BK][28];    // [n-group][k][col, padded 25->28]

  const int tid  = threadIdx.x;
  const int lane = tid & 63;
  const int ng   = tid >> 6;                 // 0..3
  const size_t r0 = (size_t)blockIdx.x * BM;

  float acc[4][25];
#pragma unroll
  for (int i = 0; i < 4; ++i)
#pragma unroll
    for (int c = 0; c < 25; ++c) acc[i][c] = 0.0f;

  const int rowld = tid >> 2;  // 0..63 (X staging row within 64-row rep)
  const int kq    = tid & 3;   // float4 index along k

  for (int kt = 0; kt < KDIM; kt += BK) {
    // stage X tile: 256 rows x 16 k, transposed into Xs[k][m]
#pragma unroll
    for (int rep = 0; rep < 4; ++rep) {
      const int row = rowld + rep * 64;
      const float4 v = *(const float4*)(X + (r0 + row) * KDIM + kt + kq * 4);
      Xs[kq * 4 + 0][row] = v.x;
      Xs[kq * 4 + 1][row] = v.y;
      Xs[kq * 4 + 2][row] = v.z;
      Xs[kq * 4 + 3][row] = v.w;
    }
    // stage W tile: 100 n x 16 k = 400 float4
    for (int i = tid; i < 400; i += 256) {
      const int n   = i >> 2;
      const int kq2 = i & 3;
      const float4 v = *(const float4*)(W1 + (size_t)n * KDIM + kt + kq2 * 4);
      const int g = n / 25;
      const int c = n % 25;
      Ws[g][kq2 * 4 + 0][c] = v.x;
      Ws[g][kq2 * 4 + 1][c] = v.y;
      Ws[g][kq2 * 4 + 2][c] = v.z;
      Ws[g][kq2 * 4 + 3][c] = v.w;
    }
    __syncthreads();

#pragma unroll
    for (int k = 0; k < BK; ++k) {
      const float a0 = Xs[k][4 * lane + 0];
      const float a1 = Xs[k][4 * lane + 1];
      const float a2 = Xs[k][4 * lane + 2];
      const float a3 = Xs[k][4 * lane + 3];
#pragma unroll
      for (int c = 0; c < 25; ++c) {
        const float bv = Ws[ng][k][c];   // wave-uniform -> LDS broadcast
        acc[0][c] = fmaf(a0, bv, acc[0][c]);
        acc[1][c] = fmaf(a1, bv, acc[1][c]);
        acc[2][c] = fmaf(a2, bv, acc[2][c]);
        acc[3][c] = fmaf(a3, bv, acc[3][c]);
      }
    }
    __syncthreads();
  }

  // store: rows r0 + 4*lane + i, cols ng*25 + c (25 consecutive floats/row)
#pragma unroll
  for (int i = 0; i < 4; ++i) {
    float* up = U + (r0 + 4 * lane + i) * NHID + ng * 25;
#pragma unroll
    for (int c = 0; c < 25; ++c) up[c] = acc[i][c];
  }
}

// ---------------------------------------------------------------------------
// Kernel 2: per-(batch, hidden) scan over 100 steps + fused 10x100 output GEMM.
// One block per batch; lane j < 100 runs one independent chain.
// ---------------------------------------------------------------------------
__global__ __launch_bounds__(128)
void snn_scan(const float* __restrict__ U, const float* __restrict__ b1,
              const float* __restrict__ wsyn1p, const float* __restrict__ wsyn2p,
              const float* __restrict__ W2, const float* __restrict__ b2,
              float* __restrict__ out) {
  const int b = blockIdx.x;
  const int j = threadIdx.x;
  __shared__ float zsh[NHID];

  const float inv1 = 1.0f / (1.0f + expf(-wsyn1p[0]));
  const float inv2 = 1.0f / (1.0f + expf(-wsyn2p[0]));

  if (j < NHID) {
    const float* __restrict__ Up = U + (size_t)b * NSTEPS * NHID + j;
    const float bj = b1[j];
    float S = 0.0f, v1 = 0.0f, s2 = 0.0f, z = 0.0f;
    float at = 0x1p-100f;  // 2^(t-100), t=0

    float ubuf[8];  // depth-8 prefetch to hide HBM latency
#pragma unroll
    for (int p = 0; p < 8; ++p) ubuf[p] = Up[p * NHID];

#pragma unroll
    for (int t = 0; t < NSTEPS; ++t) {
      const float u = ubuf[t & 7];
      if (t + 8 < NSTEPS) ubuf[t & 7] = Up[(t + 8) * NHID];

      S = S - S * inv1 + u;                 // SynapseFilter 1 (in h-space)
      const float h = S + bj;
      v1 = v1 + (h - v1) * 0.5f;            // LIF1, tau=2
      const float sp = (v1 - 1.0f >= 0.0f) ? 1.0f : 0.0f;
      v1 = v1 * (1.0f - sp);                // hard reset
      s2 = s2 - s2 * inv2 + sp;             // SynapseFilter 2
      z  = fmaf(at, s2, z);                 // v2 contribution weight 2^(t-100)
      at *= 2.0f;
    }
    zsh[j] = z;
  }
  __syncthreads();

  if (j < 10) {
    float accv = b2[j];
    const float* w = W2 + j * NHID;
#pragma unroll
    for (int jj = 0; jj < NHID; ++jj) accv = fmaf(zsh[jj], w[jj], accv);
    out[(size_t)b * 10 + j] = accv;
  }
}

extern "C" void kernel_launch(void* const* d_in, const int* in_sizes, int n_in,
                              void* d_out, int out_size, void* d_ws, size_t ws_size,
                              hipStream_t stream) {
  const float* x     = (const float*)d_in[0];
  const float* wsyn1 = (const float*)d_in[1];
  const float* W1    = (const float*)d_in[2];
  const float* b1    = (const float*)d_in[3];
  const float* wsyn2 = (const float*)d_in[4];
  const float* W2    = (const float*)d_in[5];
  const float* b2    = (const float*)d_in[6];
  float* out = (float*)d_out;

  float* U = (float*)d_ws;  // 102400 x 100 fp32 = 40.96 MB scratch

  snn_gemm1<<<dim3(400), dim3(256), 0, stream>>>(x, W1, U);
  snn_scan<<<dim3(1024), dim3(128), 0, stream>>>(U, b1, wsyn1, wsyn2, W2, b2, out);
}

// Round 2
// 642.335 us; speedup vs baseline: 1.1040x; 1.1040x over previous
//
#include <hip/hip_runtime.h>
#include <math.h>

// Fully fused SNN forward. Linearity collapse (verified R1, absmax 4.8e-7):
//   U[b,t,j] = (x[b,t] @ W1^T)[j]
//   S_t = S_{t-1}(1-inv1) + U_t ; h = S + b1 ; v1 = (v1+h)/2 ; sp = (v1>=1);
//   v1 *= (1-sp) ; s2 = s2(1-inv2) + sp ; v2 = sum_t 2^(t-100) (s2@W2^T + b2)
//      = z @ W2^T + b2,  z[j] = sum_t 2^(t-100) s2_t[j].
//
// One block per batch (grid 1024 = 4 blocks/CU exactly). Block computes the
// 100x100 U tile in registers (rows padded to 128, cols to 112), then scans
// t in 4 chunks of 25 through LDS, then the 10-col output dot.
//
// Per wave per k: 1 ds_read_b64 (2 X rows, interleaved layout) +
// 7 uniform ds_read_b128 (28 W cols, broadcast) + 56 v_fma -> 7:1 FMA:LDS.

#define NSTEPS 100
#define NHID 100
#define KDIM 784
#define BK 16
#define NOUT 10

__global__ __launch_bounds__(256, 4)
void snn_fused(const float* __restrict__ X, const float* __restrict__ wsyn1p,
               const float* __restrict__ W1, const float* __restrict__ b1,
               const float* __restrict__ wsyn2p, const float* __restrict__ W2,
               const float* __restrict__ b2, float* __restrict__ out) {
  // Xs: k-major, rows interleaved: Xs[k][2r] = row r, Xs[k][2r+1] = row r+64.
  // Stride 130 keeps 8B alignment for the b64 read (520 % 8 == 0).
  __shared__ float Xs[BK][130];
  __shared__ float Ws[BK][104];   // k-major W tile, cols padded 100->104
  __shared__ float Cs[25][104];   // one 25-timestep chunk of U for the scan
  __shared__ float zsh[NHID];

  const int tid = threadIdx.x;
  const int l   = tid & 63;
  const int wu  = __builtin_amdgcn_readfirstlane(tid >> 6);  // wave id 0..3
  const int cbase = 28 * wu;      // this wave's first col (16B-aligned)
  const long b  = blockIdx.x;
  const float* __restrict__ Xb = X + b * (NSTEPS * KDIM);

  float acc0[28], acc1[28];       // rows l and l+64, cols cbase..cbase+27
#pragma unroll
  for (int c = 0; c < 28; ++c) { acc0[c] = 0.f; acc1[c] = 0.f; }

  const int sr  = tid >> 2;       // staging row 0..63
  const int skq = tid & 3;        // staging float4 k-index

  for (int kt = 0; kt < KDIM; kt += BK) {
    // ---- stage X: rows sr and sr+64 (clamp t>=100 to 99; results discarded)
    const float4 va = *(const float4*)(Xb + sr * KDIM + kt + 4 * skq);
    const int t1 = (sr + 64 < NSTEPS) ? (sr + 64) : (NSTEPS - 1);
    const float4 vb = *(const float4*)(Xb + t1 * KDIM + kt + 4 * skq);
    {
      float2 p0 = {va.x, vb.x}, p1 = {va.y, vb.y};
      float2 p2 = {va.z, vb.z}, p3 = {va.w, vb.w};
      *(float2*)&Xs[4 * skq + 0][2 * sr] = p0;
      *(float2*)&Xs[4 * skq + 1][2 * sr] = p1;
      *(float2*)&Xs[4 * skq + 2][2 * sr] = p2;
      *(float2*)&Xs[4 * skq + 3][2 * sr] = p3;
    }
    // ---- stage W: 100 cols x 16 k = 400 float4
    for (int i = tid; i < 4 * NHID; i += 256) {
      const int j = i >> 2, kq = i & 3;
      const float4 v = *(const float4*)(W1 + (size_t)j * KDIM + kt + 4 * kq);
      Ws[4 * kq + 0][j] = v.x;
      Ws[4 * kq + 1][j] = v.y;
      Ws[4 * kq + 2][j] = v.z;
      Ws[4 * kq + 3][j] = v.w;
    }
    __syncthreads();

#pragma unroll
    for (int k = 0; k < BK; ++k) {
      const float2 xp = *(const float2*)&Xs[k][2 * l];  // rows l, l+64
#pragma unroll
      for (int c4 = 0; c4 < 7; ++c4) {
        const float4 wv = *(const float4*)&Ws[k][cbase + 4 * c4];  // uniform
        acc0[4*c4+0] = fmaf(xp.x, wv.x, acc0[4*c4+0]);
        acc0[4*c4+1] = fmaf(xp.x, wv.y, acc0[4*c4+1]);
        acc0[4*c4+2] = fmaf(xp.x, wv.z, acc0[4*c4+2]);
        acc0[4*c4+3] = fmaf(xp.x, wv.w, acc0[4*c4+3]);
        acc1[4*c4+0] = fmaf(xp.y, wv.x, acc1[4*c4+0]);
        acc1[4*c4+1] = fmaf(xp.y, wv.y, acc1[4*c4+1]);
        acc1[4*c4+2] = fmaf(xp.y, wv.z, acc1[4*c4+2]);
        acc1[4*c4+3] = fmaf(xp.y, wv.w, acc1[4*c4+3]);
      }
    }
    __syncthreads();
  }

  // ---- fused scan epilogue: 4 chunks of 25 timesteps through Cs
  const float inv1 = 1.f / (1.f + expf(-wsyn1p[0]));
  const float inv2 = 1.f / (1.f + expf(-wsyn2p[0]));
  const float bj = (tid < NHID) ? b1[tid] : 0.f;
  const int ncols = (cbase + 28 <= NHID) ? 28 : (NHID - cbase);  // 28,28,28,16
  float S = 0.f, v1 = 0.f, s2 = 0.f, z = 0.f;
  float at = 0x1p-100f;  // 2^(t-100)

  for (int q = 0; q < 4; ++q) {
    const int r0 = l - 25 * q;        // chunk-row of acc0 (t = l)
    const int r1 = l + 64 - 25 * q;   // chunk-row of acc1 (t = l+64)
    if (r0 >= 0 && r0 < 25) {
      for (int c = 0; c < ncols; ++c) Cs[r0][cbase + c] = acc0[c];
    }
    if (r1 >= 0 && r1 < 25) {
      for (int c = 0; c < ncols; ++c) Cs[r1][cbase + c] = acc1[c];
    }
    __syncthreads();
    if (tid < NHID) {
#pragma unroll
      for (int tt = 0; tt < 25; ++tt) {
        const float u = Cs[tt][tid];
        S = S - S * inv1 + u;             // SynapseFilter 1 (h-space)
        const float h = S + bj;
        v1 = v1 + (h - v1) * 0.5f;        // LIF1, tau=2
        const float sp = (v1 >= 1.0f) ? 1.0f : 0.0f;
        v1 = v1 * (1.0f - sp);            // hard reset
        s2 = s2 - s2 * inv2 + sp;         // SynapseFilter 2
        z  = fmaf(at, s2, z);
        at *= 2.0f;
      }
    }
    __syncthreads();
  }

  if (tid < NHID) zsh[tid] = z;
  __syncthreads();

  if (tid < NOUT) {
    float a = b2[tid];
    const float* __restrict__ wrow = W2 + tid * NHID;
#pragma unroll
    for (int jj = 0; jj < NHID; ++jj) a = fmaf(zsh[jj], wrow[jj], a);
    out[b * NOUT + tid] = a;
  }
}

extern "C" void kernel_launch(void* const* d_in, const int* in_sizes, int n_in,
                              void* d_out, int out_size, void* d_ws, size_t ws_size,
                              hipStream_t stream) {
  const float* x     = (const float*)d_in[0];
  const float* wsyn1 = (const float*)d_in[1];
  const float* W1    = (const float*)d_in[2];
  const float* b1    = (const float*)d_in[3];
  const float* wsyn2 = (const float*)d_in[4];
  const float* W2    = (const float*)d_in[5];
  const float* b2    = (const float*)d_in[6];
  float* out = (float*)d_out;

  snn_fused<<<dim3(1024), dim3(256), 0, stream>>>(x, wsyn1, W1, b1, wsyn2, W2,
                                                  b2, out);
}

// Round 3
// 561.728 us; speedup vs baseline: 1.2625x; 1.1435x over previous
//
#include <hip/hip_runtime.h>
#include <math.h>

// Fully fused SNN forward (linearity collapse verified R1/R2, absmax 4.8e-7).
// R3: 2 batches per block, 4 consecutive U-rows per lane (one ds_read_b128),
// 25 exact cols per wave (no col padding), register-prefetched K-tiles.
// Per wave per k: 1 b128 (X, 4 rows) + 6 b128 + 1 b32 (W, uniform broadcast)
// feeding 100 FMAs -> LDS:VALU ~0.6, VALU-bound by design.

#define NSTEPS 100
#define NHID 100
#define KDIM 784
#define BK 16
#define NOUT 10

__global__ __launch_bounds__(256, 2)
void snn_fused2(const float* __restrict__ X, const float* __restrict__ wsyn1p,
                const float* __restrict__ W1, const float* __restrict__ b1,
                const float* __restrict__ wsyn2p, const float* __restrict__ W2,
                const float* __restrict__ b2, float* __restrict__ out) {
  __shared__ float Xs[BK][256];      // Xs[k][r]: U-row r (r=batchhalf*128+t)
  __shared__ float Ws[BK][112];      // Ws[k][28*cg + c]: W1[25*cg+c][k]
  __shared__ float Cs[2][25][106];   // scan chunk, stride 106 breaks conflicts
  __shared__ float zsh[2][NHID];

  const int tid = threadIdx.x;
  const int l   = tid & 63;
  const int cg  = __builtin_amdgcn_readfirstlane(tid >> 6);  // col group 0..3
  const long b0 = 2L * blockIdx.x;   // batches b0, b0+1

  // ---- staging identities: thread stages U-row `tid`
  const int sb = tid >> 7;                                   // batch half
  const int st = ((tid & 127) < NSTEPS) ? (tid & 127) : (NSTEPS - 1);
  const float* __restrict__ Xrow = X + ((b0 + sb) * NSTEPS + st) * (size_t)KDIM;
  const int wj0 = tid >> 2, wkq = tid & 3;                   // W float4 item 0
  const int g0 = wj0 / 25, c0 = wj0 % 25;
  const int wj1 = wj0 + 64;                                  // item 1 (tid<144)
  const int g1 = wj1 / 25, c1 = wj1 % 25;
  const float* __restrict__ Wp0 = W1 + (size_t)wj0 * KDIM + 4 * wkq;
  const float* __restrict__ Wp1 = W1 + (size_t)wj1 * KDIM + 4 * wkq;

  float acc[4][25];
#pragma unroll
  for (int i = 0; i < 4; ++i)
#pragma unroll
    for (int c = 0; c < 25; ++c) acc[i][c] = 0.0f;

  // ---- prefetch tile kt=0 into registers
  float4 xr0 = *(const float4*)(Xrow + 0);
  float4 xr1 = *(const float4*)(Xrow + 4);
  float4 xr2 = *(const float4*)(Xrow + 8);
  float4 xr3 = *(const float4*)(Xrow + 12);
  float4 wr0 = *(const float4*)(Wp0);
  float4 wr1 = (tid < 144) ? *(const float4*)(Wp1) : float4{0, 0, 0, 0};

  for (int kt = 0; kt < KDIM; kt += BK) {
    __syncthreads();   // previous tile's LDS reads complete
    // write staged tile (stride-1 lane addressing: conflict-free)
    Xs[0][tid] = xr0.x;  Xs[1][tid] = xr0.y;  Xs[2][tid] = xr0.z;  Xs[3][tid] = xr0.w;
    Xs[4][tid] = xr1.x;  Xs[5][tid] = xr1.y;  Xs[6][tid] = xr1.z;  Xs[7][tid] = xr1.w;
    Xs[8][tid] = xr2.x;  Xs[9][tid] = xr2.y;  Xs[10][tid] = xr2.z; Xs[11][tid] = xr2.w;
    Xs[12][tid] = xr3.x; Xs[13][tid] = xr3.y; Xs[14][tid] = xr3.z; Xs[15][tid] = xr3.w;
    {
      float* w = &Ws[4 * wkq][28 * g0 + c0];
      w[0] = wr0.x; w[112] = wr0.y; w[224] = wr0.z; w[336] = wr0.w;
    }
    if (tid < 144) {
      float* w = &Ws[4 * wkq][28 * g1 + c1];
      w[0] = wr1.x; w[112] = wr1.y; w[224] = wr1.z; w[336] = wr1.w;
    }
    __syncthreads();
    // issue next tile's global loads now; vmcnt drains after compute
    if (kt + BK < KDIM) {
      const float* xp = Xrow + kt + BK;
      xr0 = *(const float4*)(xp + 0);
      xr1 = *(const float4*)(xp + 4);
      xr2 = *(const float4*)(xp + 8);
      xr3 = *(const float4*)(xp + 12);
      wr0 = *(const float4*)(Wp0 + kt + BK);
      if (tid < 144) wr1 = *(const float4*)(Wp1 + kt + BK);
    }
#pragma unroll
    for (int k = 0; k < BK; ++k) {
      const float4 xv = *(const float4*)&Xs[k][4 * l];   // rows 4l..4l+3
      const float* __restrict__ wk = &Ws[k][28 * cg];    // wave-uniform
#pragma unroll
      for (int g = 0; g < 6; ++g) {
        const float4 wv = *(const float4*)(wk + 4 * g);
        acc[0][4*g+0] = fmaf(xv.x, wv.x, acc[0][4*g+0]);
        acc[1][4*g+0] = fmaf(xv.y, wv.x, acc[1][4*g+0]);
        acc[2][4*g+0] = fmaf(xv.z, wv.x, acc[2][4*g+0]);
        acc[3][4*g+0] = fmaf(xv.w, wv.x, acc[3][4*g+0]);
        acc[0][4*g+1] = fmaf(xv.x, wv.y, acc[0][4*g+1]);
        acc[1][4*g+1] = fmaf(xv.y, wv.y, acc[1][4*g+1]);
        acc[2][4*g+1] = fmaf(xv.z, wv.y, acc[2][4*g+1]);
        acc[3][4*g+1] = fmaf(xv.w, wv.y, acc[3][4*g+1]);
        acc[0][4*g+2] = fmaf(xv.x, wv.z, acc[0][4*g+2]);
        acc[1][4*g+2] = fmaf(xv.y, wv.z, acc[1][4*g+2]);
        acc[2][4*g+2] = fmaf(xv.z, wv.z, acc[2][4*g+2]);
        acc[3][4*g+2] = fmaf(xv.w, wv.z, acc[3][4*g+2]);
        acc[0][4*g+3] = fmaf(xv.x, wv.w, acc[0][4*g+3]);
        acc[1][4*g+3] = fmaf(xv.y, wv.w, acc[1][4*g+3]);
        acc[2][4*g+3] = fmaf(xv.z, wv.w, acc[2][4*g+3]);
        acc[3][4*g+3] = fmaf(xv.w, wv.w, acc[3][4*g+3]);
      }
      const float w24 = wk[24];
      acc[0][24] = fmaf(xv.x, w24, acc[0][24]);
      acc[1][24] = fmaf(xv.y, w24, acc[1][24]);
      acc[2][24] = fmaf(xv.z, w24, acc[2][24]);
      acc[3][24] = fmaf(xv.w, w24, acc[3][24]);
    }
  }

  // ---- fused scan epilogue: 4 chunks of 25 timesteps, 2 batches in parallel
  const float inv1 = 1.f / (1.f + expf(-wsyn1p[0]));
  const float inv2 = 1.f / (1.f + expf(-wsyn2p[0]));
  const int sb2 = tid >> 7;          // scan identity: batch half
  const int j   = tid & 127;         // hidden index (active if < 100)
  const float bj = (j < NHID) ? b1[j] : 0.f;
  float S = 0.f, v1 = 0.f, s2 = 0.f, z = 0.f;
  float at = 0x1p-100f;              // 2^(t-100)

  for (int q = 0; q < 4; ++q) {
    __syncthreads();   // previous chunk's reads complete
#pragma unroll
    for (int i = 0; i < 4; ++i) {
      const int r = 4 * l + i;
      const int bb = r >> 7;
      const int t  = r & 127;
      const int tt = t - 25 * q;
      if (t < NSTEPS && tt >= 0 && tt < 25) {
#pragma unroll
        for (int c = 0; c < 25; ++c) Cs[bb][tt][25 * cg + c] = acc[i][c];
      }
    }
    __syncthreads();
    if (j < NHID) {
#pragma unroll
      for (int tt = 0; tt < 25; ++tt) {
        const float u = Cs[sb2][tt][j];
        S = S - S * inv1 + u;             // SynapseFilter 1 (h-space)
        const float h = S + bj;
        v1 = v1 + (h - v1) * 0.5f;        // LIF1, tau=2
        const float sp = (v1 >= 1.0f) ? 1.0f : 0.0f;
        v1 = v1 * (1.0f - sp);            // hard reset
        s2 = s2 - s2 * inv2 + sp;         // SynapseFilter 2
        z  = fmaf(at, s2, z);
        at *= 2.0f;
      }
    }
  }

  if (j < NHID) zsh[sb2][j] = z;
  __syncthreads();

  if (tid < 2 * NOUT) {
    const int bb = tid / NOUT;
    const int jo = tid % NOUT;
    float a = b2[jo];
    const float* __restrict__ wrow = W2 + jo * NHID;
#pragma unroll
    for (int jj = 0; jj < NHID; ++jj) a = fmaf(zsh[bb][jj], wrow[jj], a);
    out[(b0 + bb) * NOUT + jo] = a;
  }
}

extern "C" void kernel_launch(void* const* d_in, const int* in_sizes, int n_in,
                              void* d_out, int out_size, void* d_ws, size_t ws_size,
                              hipStream_t stream) {
  const float* x     = (const float*)d_in[0];
  const float* wsyn1 = (const float*)d_in[1];
  const float* W1    = (const float*)d_in[2];
  const float* b1    = (const float*)d_in[3];
  const float* wsyn2 = (const float*)d_in[4];
  const float* W2    = (const float*)d_in[5];
  const float* b2    = (const float*)d_in[6];
  float* out = (float*)d_out;

  snn_fused2<<<dim3(512), dim3(256), 0, stream>>>(x, wsyn1, W1, b1, wsyn2, W2,
                                                  b2, out);
}

// Round 4
// 554.085 us; speedup vs baseline: 1.2799x; 1.0138x over previous
//
#include <hip/hip_runtime.h>
#include <math.h>

// Fully fused SNN forward (linearity collapse verified R1-R3, absmax 4.8e-7).
// R4: (1) W1 pre-transposed to Wt[784][128] and read via wave-uniform
// addresses -> SMEM s_load (scalar pipe), removing 86% of LDS issue traffic
// (R3 model: 720 LDS-cyc/CU/k vs 400 VALU -> LDS-bound at 235us).
// (2) col-paired accumulators with __builtin_elementwise_fma on
// ext_vector(2) float -> v_pk_fma_f32: 2 FMA/inst, VALU floor 131->73us.

#define NSTEPS 100
#define NHID 100
#define KDIM 784
#define BKT 28        // 784 = 28 * 28 exact
#define NOUT 10

typedef float v2f __attribute__((ext_vector_type(2)));

// ---- tiny transpose: Wt[k][32*cg + i] = W1[25*cg + i][k], pad i>=25 with 0
__global__ __launch_bounds__(256)
void wt_transpose(const float* __restrict__ W1, float* __restrict__ Wt) {
  const int idx = blockIdx.x * 256 + threadIdx.x;   // 784*128 entries
  if (idx >= KDIM * 128) return;
  const int k = idx >> 7, s = idx & 127, cg = s >> 5, i = s & 31;
  const int j = 25 * cg + i;
  Wt[idx] = (i < 25) ? W1[(size_t)j * KDIM + k] : 0.0f;
}

__global__ __launch_bounds__(256, 2)
void snn_fused3(const float* __restrict__ X, const float* __restrict__ Wt,
                const float* __restrict__ wsyn1p, const float* __restrict__ b1,
                const float* __restrict__ wsyn2p, const float* __restrict__ W2,
                const float* __restrict__ b2, float* __restrict__ out) {
  __shared__ float Xs[BKT][256];     // 28.7 KB: U-row-major X tile
  __shared__ float Cs[2][25][106];   // scan chunk, stride 106 breaks conflicts
  __shared__ float zsh[2][NHID];

  const int tid = threadIdx.x;
  const int l   = tid & 63;
  const int cg  = __builtin_amdgcn_readfirstlane(tid >> 6);  // wave col group
  const long b0 = 2L * blockIdx.x;

  // staging identity: thread stages U-row `tid` (t>=100 clamped, discarded)
  const int sb = tid >> 7;
  const int st = ((tid & 127) < NSTEPS) ? (tid & 127) : (NSTEPS - 1);
  const float* __restrict__ Xrow = X + ((b0 + sb) * NSTEPS + st) * (size_t)KDIM;

  v2f  acc2[4][12];                  // rows 4l..4l+3, col pairs 0..23
  float accs[4];                     // col 24
#pragma unroll
  for (int i = 0; i < 4; ++i) {
    accs[i] = 0.0f;
#pragma unroll
    for (int c = 0; c < 12; ++c) acc2[i][c] = (v2f){0.0f, 0.0f};
  }

  float4 pf[7];                      // prefetched 28-float X row segment
#pragma unroll
  for (int q = 0; q < 7; ++q) pf[q] = *(const float4*)(Xrow + 4 * q);

  const float* __restrict__ wgrp = Wt + 32 * cg;   // uniform -> SMEM path

  for (int kt = 0; kt < KDIM; kt += BKT) {
    __syncthreads();                 // previous tile's LDS reads complete
#pragma unroll
    for (int q = 0; q < 7; ++q) {
      Xs[4 * q + 0][tid] = pf[q].x;
      Xs[4 * q + 1][tid] = pf[q].y;
      Xs[4 * q + 2][tid] = pf[q].z;
      Xs[4 * q + 3][tid] = pf[q].w;
    }
    __syncthreads();
    if (kt + BKT < KDIM) {
      const float* xp = Xrow + kt + BKT;
#pragma unroll
      for (int q = 0; q < 7; ++q) pf[q] = *(const float4*)(xp + 4 * q);
    }

#pragma unroll 4
    for (int k = 0; k < BKT; ++k) {
      const float4 xv = *(const float4*)&Xs[k][4 * l];
      const float* __restrict__ wk = wgrp + (size_t)(kt + k) * 128;  // uniform
      float w[26];
#pragma unroll
      for (int i2 = 0; i2 < 13; ++i2)
        *(v2f*)(w + 2 * i2) = *(const v2f*)(wk + 2 * i2);  // s_load pairs

      const v2f xd0 = {xv.x, xv.x};
      const v2f xd1 = {xv.y, xv.y};
      const v2f xd2 = {xv.z, xv.z};
      const v2f xd3 = {xv.w, xv.w};
#pragma unroll
      for (int c2 = 0; c2 < 12; ++c2) {
        const v2f wv = *(const v2f*)(w + 2 * c2);
        acc2[0][c2] = __builtin_elementwise_fma(xd0, wv, acc2[0][c2]);
        acc2[1][c2] = __builtin_elementwise_fma(xd1, wv, acc2[1][c2]);
        acc2[2][c2] = __builtin_elementwise_fma(xd2, wv, acc2[2][c2]);
        acc2[3][c2] = __builtin_elementwise_fma(xd3, wv, acc2[3][c2]);
      }
      const float w24 = w[24];
      accs[0] = fmaf(xv.x, w24, accs[0]);
      accs[1] = fmaf(xv.y, w24, accs[1]);
      accs[2] = fmaf(xv.z, w24, accs[2]);
      accs[3] = fmaf(xv.w, w24, accs[3]);
    }
  }

  // ---- fused scan epilogue: 4 chunks of 25 timesteps, 2 batches in parallel
  const float inv1 = 1.f / (1.f + expf(-wsyn1p[0]));
  const float inv2 = 1.f / (1.f + expf(-wsyn2p[0]));
  const int sb2 = tid >> 7;
  const int j   = tid & 127;
  const float bj = (j < NHID) ? b1[j] : 0.f;
  float S = 0.f, v1 = 0.f, s2 = 0.f, z = 0.f;
  float at = 0x1p-100f;              // 2^(t-100)

  for (int q = 0; q < 4; ++q) {
    __syncthreads();                 // previous chunk's reads complete
#pragma unroll
    for (int i = 0; i < 4; ++i) {
      const int r  = 4 * l + i;
      const int bb = r >> 7;
      const int t  = r & 127;
      const int tt = t - 25 * q;
      if (t < NSTEPS && tt >= 0 && tt < 25) {
        float* crow = &Cs[bb][tt][25 * cg];
#pragma unroll
        for (int c2 = 0; c2 < 12; ++c2) {
          crow[2 * c2 + 0] = acc2[i][c2].x;
          crow[2 * c2 + 1] = acc2[i][c2].y;
        }
        crow[24] = accs[i];
      }
    }
    __syncthreads();
    if (j < NHID) {
#pragma unroll
      for (int tt = 0; tt < 25; ++tt) {
        const float u = Cs[sb2][tt][j];
        S = S - S * inv1 + u;             // SynapseFilter 1 (h-space)
        const float h = S + bj;
        v1 = v1 + (h - v1) * 0.5f;        // LIF1, tau=2
        const float sp = (v1 >= 1.0f) ? 1.0f : 0.0f;
        v1 = v1 * (1.0f - sp);            // hard reset
        s2 = s2 - s2 * inv2 + sp;         // SynapseFilter 2
        z  = fmaf(at, s2, z);
        at *= 2.0f;
      }
    }
  }

  if (j < NHID) zsh[sb2][j] = z;
  __syncthreads();

  if (tid < 2 * NOUT) {
    const int bb = tid / NOUT;
    const int jo = tid % NOUT;
    float a = b2[jo];
    const float* __restrict__ wrow = W2 + jo * NHID;
#pragma unroll
    for (int jj = 0; jj < NHID; ++jj) a = fmaf(zsh[bb][jj], wrow[jj], a);
    out[(b0 + bb) * NOUT + jo] = a;
  }
}

extern "C" void kernel_launch(void* const* d_in, const int* in_sizes, int n_in,
                              void* d_out, int out_size, void* d_ws, size_t ws_size,
                              hipStream_t stream) {
  const float* x     = (const float*)d_in[0];
  const float* wsyn1 = (const float*)d_in[1];
  const float* W1    = (const float*)d_in[2];
  const float* b1    = (const float*)d_in[3];
  const float* wsyn2 = (const float*)d_in[4];
  const float* W2    = (const float*)d_in[5];
  const float* b2    = (const float*)d_in[6];
  float* out = (float*)d_out;
  float* Wt  = (float*)d_ws;   // 784 x 128 fp32 = 401 KB

  wt_transpose<<<dim3((KDIM * 128 + 255) / 256), dim3(256), 0, stream>>>(W1, Wt);
  snn_fused3<<<dim3(512), dim3(256), 0, stream>>>(x, Wt, wsyn1, b1, wsyn2, W2,
                                                  b2, out);
}